// Round 8
// baseline (381.960 us; speedup 1.0000x reference)
//
#include <hip/hip_runtime.h>

// ---------------- problem constants ----------------
#define NN    10000          // nodes
#define FIN   2000           // input features
#define NH    10             // heads
#define C1    128            // layer-1 out channels per head
#define C2    64             // layer-2 out channels per head
#define HC1   1280           // NH*C1
#define HC2   640            // NH*C2
#define MP    10240          // nodes padded to 256*40
#define K1P   2016           // FIN padded to 32 multiple (63*32)

typedef _Float16 f16x8 __attribute__((ext_vector_type(8)));
typedef _Float16 f16x4 __attribute__((ext_vector_type(4)));
typedef _Float16 f16x2 __attribute__((ext_vector_type(2)));
typedef float    f32x4 __attribute__((ext_vector_type(4)));

__device__ __forceinline__ float leaky(float x) { return x > 0.f ? x : 0.2f * x; }

// ---------------- fused prep: cast x->fp16, transpose W1, transpose W2, edge count ----------------
// (r2 arrangement — best measured gemm1 era; counts must be zeroed by prior memset)
#define NCAST (2 * MP)        // 2 blocks per row (Cp4=504)
#define NW1   (63 * 40)
#define NW2   (40 * 20)
__global__ void k_prep(const float* __restrict__ x, _Float16* __restrict__ A1,
                       const float* __restrict__ W1, _Float16* __restrict__ W1t,
                       const float* __restrict__ W2, _Float16* __restrict__ W2t,
                       const int* __restrict__ ei, int* __restrict__ counts, int E) {
    __shared__ float tile[32][33];
    int bid = blockIdx.x, t = threadIdx.x;
    if (bid < NCAST) {
        int r = bid >> 1;
        int c = (bid & 1) * 256 + t;
        if (c >= K1P / 4) return;
        float4 v = make_float4(0.f, 0.f, 0.f, 0.f);
        if (r < NN && c < FIN / 4) v = *(const float4*)(x + (long)r * FIN + 4 * c);
        f16x4 o = {(_Float16)v.x, (_Float16)v.y, (_Float16)v.z, (_Float16)v.w};
        *(f16x4*)(A1 + (long)r * K1P + 4 * c) = o;
        return;
    }
    const float* W; _Float16* Wt; int K, N, Kpad, kbase, nbase;
    if (bid < NCAST + NW1) {
        int i = bid - NCAST;
        W = W1; Wt = W1t; K = FIN; N = HC1; Kpad = K1P;
        kbase = (i % 63) * 32; nbase = (i / 63) * 32;
    } else if (bid < NCAST + NW1 + NW2) {
        int i = bid - NCAST - NW1;
        W = W2; Wt = W2t; K = HC1; N = HC2; Kpad = HC1;
        kbase = (i % 40) * 32; nbase = (i / 40) * 32;
    } else {
        int e = (bid - NCAST - NW1 - NW2) * 256 + t;
        if (e < E) atomicAdd(&counts[ei[E + e]], 1);
        return;
    }
    int tx = t & 31, ty = t >> 5;
#pragma unroll
    for (int i = 0; i < 4; i++) {
        int k = kbase + ty + i * 8;
        float v = (k < K) ? W[(long)k * N + nbase + tx] : 0.0f;
        tile[ty + i * 8][tx] = v;
    }
    __syncthreads();
#pragma unroll
    for (int i = 0; i < 4; i++) {
        int n = nbase + ty + i * 8;
        Wt[(long)n * Kpad + kbase + tx] = (_Float16)tile[tx][ty + i * 8];
    }
}

// ---------------- async global->LDS helper ----------------
__device__ __forceinline__ void gl2lds16(const void* g, void* l) {
    __builtin_amdgcn_global_load_lds((const __attribute__((address_space(1))) void*)g,
                                     (__attribute__((address_space(3))) void*)l, 16, 0, 0);
}

// ---------------- layer-1 GEMM: BM=256 x BN=256, 512 thr / 8 waves (2m x 4n) ----------------
// r2 config (best measured 69.2 us): tri-buffer depth-2, counted vmcnt, fill
// side-jobs appended. gemm1 declared CLOSED after 5 null experiments (r3-r7:
// XCD maps, depth-3, 2-slice periods) — per-CU staged-byte rate is pinned at
// ~28-30 GB/s regardless of mapping/depth/phase structure.
__global__ __launch_bounds__(512, 2) void k_gemm1(const _Float16* __restrict__ A,
                                                  const _Float16* __restrict__ Bt,
                                                  _Float16* __restrict__ C,
                                                  const float* __restrict__ asf,
                                                  const float* __restrict__ adf,
                                                  float* __restrict__ as,
                                                  float* __restrict__ ad,
                                                  int nblk,
                                                  const int* __restrict__ ei,
                                                  int* __restrict__ cursor,
                                                  int* __restrict__ colidx, int E) {
    constexpr int K    = K1P;                   // 2016
    constexpr int N    = HC1;                   // 1280
    constexpr int TBUF = 256 * 32;              // fp16 elems per A or B buffer
    __shared__ char smem[3 * TBUF * 2 * 2] __attribute__((aligned(16)));   // 96 KB
    _Float16* As = (_Float16*)smem;
    _Float16* Bs = (_Float16*)(smem + 3 * TBUF * 2);

    int bid = blockIdx.x;
    if (bid >= nblk) {                          // CSR fill side-job
        int i = (bid - nblk) * 512 + threadIdx.x;
        if (i < E + NN) {
            int s, d;
            if (i < E) { s = ei[i]; d = ei[E + i]; }
            else       { s = i - E; d = i - E; }
            int pos = atomicAdd(&cursor[d], 1);
            colidx[pos] = s;
        }
        return;
    }
    int r = bid & 7, qb = bid >> 3;
    int n_t = qb % 5;
    int m_t = r + 8 * (qb / 5);
    int m0 = m_t * 256;
    int n0 = n_t * 256;
    int t = threadIdx.x;
    int lane = t & 63, wave = t >> 6;
    int wr = wave >> 2, wc = wave & 3;          // 2 x 4 wave grid
    int lrow = lane & 15, q = lane >> 4;

    f32x4 acc[8][4] = {};

    int sS[2];
#pragma unroll
    for (int i = 0; i < 2; i++) sS[i] = t + 512 * i;
    const _Float16* Ar[2];
    const _Float16* Br[2];
#pragma unroll
    for (int i = 0; i < 2; i++) {
        int row = sS[i] >> 2, gq = (sS[i] & 3) ^ ((sS[i] >> 3) & 3);
        Ar[i] = A  + (long)(m0 + row) * K + gq * 8;
        Br[i] = Bt + (long)(n0 + row) * K + gq * 8;
    }

    int aoff[8], boff[4];
#pragma unroll
    for (int i = 0; i < 8; i++) {
        int rowa = wr * 128 + i * 16 + lrow;
        aoff[i] = rowa * 32 + ((q ^ ((rowa >> 1) & 3)) << 3);
    }
#pragma unroll
    for (int i = 0; i < 4; i++) {
        int rowb = wc * 64 + i * 16 + lrow;
        boff[i] = rowb * 32 + ((q ^ ((rowb >> 1) & 3)) << 3);
    }

    auto stage = [&](int it, int buf) {
        int k0 = it << 5;
#pragma unroll
        for (int i = 0; i < 2; i++) gl2lds16(Ar[i] + k0, &As[buf * TBUF + sS[i] * 8]);
#pragma unroll
        for (int i = 0; i < 2; i++) gl2lds16(Br[i] + k0, &Bs[buf * TBUF + sS[i] * 8]);
    };

    constexpr int WVM = 0x0F70 | 4;             // vmcnt <= loads-per-stage
    int nk = K >> 5;                            // 63
    stage(0, 0);
    stage(1, 1);
    int cur = 0;
    for (int it = 0; it < nk; it++) {
        if (it + 1 < nk) __builtin_amdgcn_s_waitcnt(WVM);
        else             __builtin_amdgcn_s_waitcnt(0x0F70);
        __builtin_amdgcn_s_barrier();
        int nxt = cur + 2; if (nxt >= 3) nxt -= 3;
        if (it + 2 < nk) stage(it + 2, nxt);

        f16x8 af[8], bf[4];
#pragma unroll
        for (int i = 0; i < 8; i++) af[i] = *(const f16x8*)&As[cur * TBUF + aoff[i]];
#pragma unroll
        for (int i = 0; i < 4; i++) bf[i] = *(const f16x8*)&Bs[cur * TBUF + boff[i]];
#pragma unroll
        for (int mt = 0; mt < 8; mt++)
#pragma unroll
            for (int nt = 0; nt < 4; nt++)
                acc[mt][nt] = __builtin_amdgcn_mfma_f32_16x16x32_f16(bf[nt], af[mt], acc[mt][nt], 0, 0, 0);
        cur = (cur + 1 == 3) ? 0 : cur + 1;
    }

    // ---- C store ----
#pragma unroll
    for (int mt = 0; mt < 8; mt++) {
        int m = m0 + wr * 128 + mt * 16 + lrow;
#pragma unroll
        for (int nt = 0; nt < 4; nt++) {
            int n = n0 + wc * 64 + nt * 16 + q * 4;
            f16x4 o = {(_Float16)acc[mt][nt][0], (_Float16)acc[mt][nt][1],
                       (_Float16)acc[mt][nt][2], (_Float16)acc[mt][nt][3]};
            *(f16x4*)(C + (long)m * N + n) = o;
        }
    }

    // ---- fused logits ----
    float4 av[4], dvv[4];
#pragma unroll
    for (int nt = 0; nt < 4; nt++) {
        av[nt]  = *(const float4*)(asf + n0 + wc * 64 + nt * 16 + q * 4);
        dvv[nt] = *(const float4*)(adf + n0 + wc * 64 + nt * 16 + q * 4);
    }
    __syncthreads();                       // done reading As/Bs; reuse smem
    float* sAs = (float*)smem;             // 256*4 floats
    float* sAd = (float*)smem + 1024;
#pragma unroll
    for (int mt = 0; mt < 8; mt++) {
        float ps = 0.f, pd = 0.f;
#pragma unroll
        for (int nt = 0; nt < 4; nt++) {
            ps += acc[mt][nt][0] * av[nt].x + acc[mt][nt][1] * av[nt].y
                + acc[mt][nt][2] * av[nt].z + acc[mt][nt][3] * av[nt].w;
            pd += acc[mt][nt][0] * dvv[nt].x + acc[mt][nt][1] * dvv[nt].y
                + acc[mt][nt][2] * dvv[nt].z + acc[mt][nt][3] * dvv[nt].w;
        }
        ps += __shfl_xor(ps, 16); ps += __shfl_xor(ps, 32);
        pd += __shfl_xor(pd, 16); pd += __shfl_xor(pd, 32);
        if (q == 0) {
            int rl = wr * 128 + mt * 16 + lrow;
            sAs[rl * 4 + wc] = ps;
            sAd[rl * 4 + wc] = pd;
        }
    }
    __syncthreads();
    if (t < 256) {
        int m = m0 + t;
        if (m < NN) {
            int hb = n0 >> 7;
            as[m * NH + hb]     = sAs[t * 4 + 0] + sAs[t * 4 + 1];
            as[m * NH + hb + 1] = sAs[t * 4 + 2] + sAs[t * 4 + 3];
            ad[m * NH + hb]     = sAd[t * 4 + 0] + sAd[t * 4 + 1];
            ad[m * NH + hb + 1] = sAd[t * 4 + 2] + sAd[t * 4 + 3];
        }
    }
}

// ---------------- generic fp16 MFMA GEMM (layer 2), BM=32*MFRAG x BN=128 ----------------
template<int MFRAG>
__global__ __launch_bounds__(256, 3) void k_gemm(const _Float16* __restrict__ A,
                                                 const _Float16* __restrict__ Bt,
                                                 _Float16* __restrict__ C, int K, int N,
                                                 int NTN,
                                                 const float* __restrict__ asf,
                                                 const float* __restrict__ adf,
                                                 float* __restrict__ as,
                                                 float* __restrict__ ad,
                                                 int headw) {
    constexpr int BM   = MFRAG * 32;
    constexpr int ABUF = BM * 32;
    constexpr int ASL  = BM / 64;
    constexpr int WVM  = 0x0F70 | (ASL + 2);
    __shared__ char smem[3 * ABUF * 2 + 3 * 8192] __attribute__((aligned(16)));
    _Float16* As = (_Float16*)smem;
    _Float16* Bs = (_Float16*)(smem + 3 * ABUF * 2);

    int bid = blockIdx.x;
    int r = bid & 7, qb = bid >> 3;
    int n_t = qb % NTN;
    int m_t = r + 8 * (qb / NTN);
    int m0 = m_t * BM;
    int n0 = n_t * 128;
    int t = threadIdx.x;
    int lane = t & 63, wave = t >> 6;
    int wr = wave >> 1, wc = wave & 1;
    int lrow = lane & 15, q = lane >> 4;

    f32x4 acc[MFRAG][4] = {};

    int sA[ASL], sB[2];
#pragma unroll
    for (int i = 0; i < ASL; i++) sA[i] = t + 256 * i;
#pragma unroll
    for (int i = 0; i < 2; i++) sB[i] = t + 256 * i;
    const _Float16* Ar[ASL];
    const _Float16* Br[2];
#pragma unroll
    for (int i = 0; i < ASL; i++) {
        int row = sA[i] >> 2, gq = (sA[i] & 3) ^ ((sA[i] >> 3) & 3);
        Ar[i] = A + (long)(m0 + row) * K + gq * 8;
    }
#pragma unroll
    for (int i = 0; i < 2; i++) {
        int row = sB[i] >> 2, gq = (sB[i] & 3) ^ ((sB[i] >> 3) & 3);
        Br[i] = Bt + (long)(n0 + row) * K + gq * 8;
    }

    int aoff[MFRAG], boff[4];
#pragma unroll
    for (int i = 0; i < MFRAG; i++) {
        int rowa = wr * (MFRAG * 16) + i * 16 + lrow;
        aoff[i] = rowa * 32 + ((q ^ ((rowa >> 1) & 3)) << 3);
    }
#pragma unroll
    for (int i = 0; i < 4; i++) {
        int rowb = wc * 64 + i * 16 + lrow;
        boff[i] = rowb * 32 + ((q ^ ((rowb >> 1) & 3)) << 3);
    }

    auto stage = [&](int it, int buf) {
        int k0 = it << 5;
#pragma unroll
        for (int i = 0; i < ASL; i++) gl2lds16(Ar[i] + k0, &As[buf * ABUF + sA[i] * 8]);
#pragma unroll
        for (int i = 0; i < 2; i++) gl2lds16(Br[i] + k0, &Bs[buf * 4096 + sB[i] * 8]);
    };

    int nk = K >> 5;
    stage(0, 0);
    stage(1, 1);
    int cur = 0;
    for (int it = 0; it < nk; it++) {
        if (it + 1 < nk) __builtin_amdgcn_s_waitcnt(WVM);
        else             __builtin_amdgcn_s_waitcnt(0x0F70);
        __builtin_amdgcn_s_barrier();
        int nxt = cur + 2; if (nxt >= 3) nxt -= 3;
        if (it + 2 < nk) stage(it + 2, nxt);

        f16x8 af[MFRAG], bf[4];
#pragma unroll
        for (int i = 0; i < MFRAG; i++) af[i] = *(const f16x8*)&As[cur * ABUF + aoff[i]];
#pragma unroll
        for (int i = 0; i < 4; i++) bf[i] = *(const f16x8*)&Bs[cur * 4096 + boff[i]];
#pragma unroll
        for (int mt = 0; mt < MFRAG; mt++)
#pragma unroll
            for (int nt = 0; nt < 4; nt++)
                acc[mt][nt] = __builtin_amdgcn_mfma_f32_16x16x32_f16(bf[nt], af[mt], acc[mt][nt], 0, 0, 0);
        cur = (cur + 1 == 3) ? 0 : cur + 1;
    }

#pragma unroll
    for (int mt = 0; mt < MFRAG; mt++) {
        int m = m0 + wr * (MFRAG * 16) + mt * 16 + lrow;
#pragma unroll
        for (int nt = 0; nt < 4; nt++) {
            int n = n0 + wc * 64 + nt * 16 + q * 4;
            f16x4 o = {(_Float16)acc[mt][nt][0], (_Float16)acc[mt][nt][1],
                       (_Float16)acc[mt][nt][2], (_Float16)acc[mt][nt][3]};
            *(f16x4*)(C + (long)m * N + n) = o;
        }
    }

    float4 av[4], dvv[4];
#pragma unroll
    for (int nt = 0; nt < 4; nt++) {
        av[nt]  = *(const float4*)(asf + n0 + wc * 64 + nt * 16 + q * 4);
        dvv[nt] = *(const float4*)(adf + n0 + wc * 64 + nt * 16 + q * 4);
    }
    __syncthreads();
    float* sAs = (float*)smem;
    float* sAd = (float*)smem + BM * 2;
#pragma unroll
    for (int mt = 0; mt < MFRAG; mt++) {
        float ps = 0.f, pd = 0.f;
#pragma unroll
        for (int nt = 0; nt < 4; nt++) {
            ps += acc[mt][nt][0] * av[nt].x + acc[mt][nt][1] * av[nt].y
                + acc[mt][nt][2] * av[nt].z + acc[mt][nt][3] * av[nt].w;
            pd += acc[mt][nt][0] * dvv[nt].x + acc[mt][nt][1] * dvv[nt].y
                + acc[mt][nt][2] * dvv[nt].z + acc[mt][nt][3] * dvv[nt].w;
        }
        ps += __shfl_xor(ps, 16); ps += __shfl_xor(ps, 32);
        pd += __shfl_xor(pd, 16); pd += __shfl_xor(pd, 32);
        if (q == 0) {
            int rl = wr * (MFRAG * 16) + mt * 16 + lrow;
            sAs[rl * 2 + wc] = ps;
            sAd[rl * 2 + wc] = pd;
        }
    }
    __syncthreads();
    if (t < BM) {
        int m = m0 + t;
        if (m < NN) {
            int hb = n0 / headw;
            if (headw == 128) {
                as[m * NH + hb] = sAs[t * 2] + sAs[t * 2 + 1];
                ad[m * NH + hb] = sAd[t * 2] + sAd[t * 2 + 1];
            } else {
                as[m * NH + hb]     = sAs[t * 2];
                as[m * NH + hb + 1] = sAs[t * 2 + 1];
                ad[m * NH + hb]     = sAd[t * 2];
                ad[m * NH + hb + 1] = sAd[t * 2 + 1];
            }
        }
    }
}

// ---------------- CSR scan ----------------
__global__ void k_scan(const int* __restrict__ counts, int* rowptr, int* cursor, int n) {
    __shared__ int s[1024];
    int t = threadIdx.x;
    const int CH = (NN + 1023) / 1024;     // 10
    int base = t * CH;
    int loc[CH];
    int sum = 0;
#pragma unroll
    for (int i = 0; i < CH; i++) {
        int idx = base + i;
        int v = (idx < n) ? (counts[idx] + 1) : 0;
        loc[i] = sum;
        sum += v;
    }
    s[t] = sum;
    __syncthreads();
    for (int off = 1; off < 1024; off <<= 1) {
        int add = (t >= off) ? s[t - off] : 0;
        __syncthreads();
        s[t] += add;
        __syncthreads();
    }
    int pre = (t > 0) ? s[t - 1] : 0;
#pragma unroll
    for (int i = 0; i < CH; i++) {
        int idx = base + i;
        if (idx < n) { int ex = pre + loc[i]; rowptr[idx] = ex; cursor[idx] = ex; }
    }
    if (t == 1023) rowptr[n] = s[1023];
}

// ---------------- layer-1 agg: HEAD-SLICED (r7 post-mortem) ----------------
// wave = (node, head); block = 4 nodes x 1 head; grid HEAD-MAJOR so at any
// instant all CUs gather from ONE 2.6 MB h1-slice (128 ch x 10240 rows) ->
// L2-resident in every XCD (temporal residency, mapping-independent), vs the
// old full-row gather whose 26 MB working set streamed from L3 (~65 us).
// Softmax in-wave via shfl broadcast: no LDS, no barriers.
__global__ __launch_bounds__(256) void k_agg1(const int* __restrict__ rowptr,
                                              const int* __restrict__ colidx,
                                              const float* __restrict__ as,
                                              const float* __restrict__ ad,
                                              const _Float16* __restrict__ h,
                                              const float* __restrict__ bias,
                                              _Float16* __restrict__ A2) {
    int bid = blockIdx.x;
    int head = bid / (MP / 4);             // MP/4 = 2560 node-groups per head
    int ng   = bid % (MP / 4);
    int wave = threadIdx.x >> 6, lane = threadIdx.x & 63;
    int n = ng * 4 + wave;
    int cb = head * C1 + 2 * lane;         // this lane's 2 channels
    if (n >= NN) {                         // pad rows: zero
        f16x2 z = {(_Float16)0.f, (_Float16)0.f};
        *(f16x2*)(A2 + (long)n * HC1 + cb) = z;
        return;
    }
    int k0 = rowptr[n], deg = rowptr[n + 1] - k0;
    float adv = ad[n * NH + head];
    float a0 = 0.f, a1 = 0.f;

    if (deg <= 64) {
        int src = (lane < deg) ? colidx[k0 + lane] : 0;
        float e = (lane < deg) ? leaky(as[(long)src * NH + head] + adv) : -1e30f;
        float m = e;
        for (int mm = 32; mm; mm >>= 1) m = fmaxf(m, __shfl_xor(m, mm));
        float x = (lane < deg) ? __expf(e - m) : 0.f;
        float s = x;
        for (int mm = 32; mm; mm >>= 1) s += __shfl_xor(s, mm);
        float alp = x / (s + 1e-16f);
        int j = 0;
        for (; j + 4 <= deg; j += 4) {
            int s0 = __shfl(src, j),     s1 = __shfl(src, j + 1);
            int s2 = __shfl(src, j + 2), s3 = __shfl(src, j + 3);
            float b0 = __shfl(alp, j),     b1 = __shfl(alp, j + 1);
            float b2 = __shfl(alp, j + 2), b3 = __shfl(alp, j + 3);
            f16x2 v0 = *(const f16x2*)(h + (long)s0 * HC1 + cb);
            f16x2 v1 = *(const f16x2*)(h + (long)s1 * HC1 + cb);
            f16x2 v2 = *(const f16x2*)(h + (long)s2 * HC1 + cb);
            f16x2 v3 = *(const f16x2*)(h + (long)s3 * HC1 + cb);
            a0 += b0 * (float)v0[0] + b1 * (float)v1[0] + b2 * (float)v2[0] + b3 * (float)v3[0];
            a1 += b0 * (float)v0[1] + b1 * (float)v1[1] + b2 * (float)v2[1] + b3 * (float)v3[1];
        }
        for (; j < deg; j++) {
            int sj = __shfl(src, j);
            float bj = __shfl(alp, j);
            f16x2 v = *(const f16x2*)(h + (long)sj * HC1 + cb);
            a0 += bj * (float)v[0];
            a1 += bj * (float)v[1];
        }
    } else {
        float m = -1e30f;
        for (int j2 = lane; j2 < deg; j2 += 64)
            m = fmaxf(m, leaky(as[(long)colidx[k0 + j2] * NH + head] + adv));
        for (int mm = 32; mm; mm >>= 1) m = fmaxf(m, __shfl_xor(m, mm));
        float s = 0.f;
        for (int j2 = lane; j2 < deg; j2 += 64)
            s += __expf(leaky(as[(long)colidx[k0 + j2] * NH + head] + adv) - m);
        for (int mm = 32; mm; mm >>= 1) s += __shfl_xor(s, mm);
        float inv = 1.f / (s + 1e-16f);
        for (int c0 = 0; c0 < deg; c0 += 64) {
            int cn = min(64, deg - c0);
            int src = (lane < cn) ? colidx[k0 + c0 + lane] : 0;
            float alp = (lane < cn)
                ? __expf(leaky(as[(long)src * NH + head] + adv) - m) * inv : 0.f;
            int j = 0;
            for (; j + 4 <= cn; j += 4) {
                int s0 = __shfl(src, j),     s1 = __shfl(src, j + 1);
                int s2 = __shfl(src, j + 2), s3 = __shfl(src, j + 3);
                float b0 = __shfl(alp, j),     b1 = __shfl(alp, j + 1);
                float b2 = __shfl(alp, j + 2), b3 = __shfl(alp, j + 3);
                f16x2 v0 = *(const f16x2*)(h + (long)s0 * HC1 + cb);
                f16x2 v1 = *(const f16x2*)(h + (long)s1 * HC1 + cb);
                f16x2 v2 = *(const f16x2*)(h + (long)s2 * HC1 + cb);
                f16x2 v3 = *(const f16x2*)(h + (long)s3 * HC1 + cb);
                a0 += b0 * (float)v0[0] + b1 * (float)v1[0] + b2 * (float)v2[0] + b3 * (float)v3[0];
                a1 += b0 * (float)v0[1] + b1 * (float)v1[1] + b2 * (float)v2[1] + b3 * (float)v3[1];
            }
            for (; j < cn; j++) {
                int sj = __shfl(src, j);
                float bj = __shfl(alp, j);
                f16x2 v = *(const f16x2*)(h + (long)sj * HC1 + cb);
                a0 += bj * (float)v[0];
                a1 += bj * (float)v[1];
            }
        }
    }
    float xb0 = a0 + bias[cb], xb1 = a1 + bias[cb + 1];
    f16x2 o = {(_Float16)(xb0 > 0.f ? xb0 : 0.f), (_Float16)(xb1 > 0.f ? xb1 : 0.f)};
    *(f16x2*)(A2 + (long)n * HC1 + cb) = o;
}

// ---------------- layer-2 agg: HEAD-SLICED, partials via atomicAdd ----------------
// wave = (node, head), lane = channel (C2=64). h2-slice per head = 1.3 MB
// (L2-resident, head-major grid). Head-mean finished by k_fin.
__global__ __launch_bounds__(256) void k_agg2(const int* __restrict__ rowptr,
                                              const int* __restrict__ colidx,
                                              const float* __restrict__ as,
                                              const float* __restrict__ ad,
                                              const _Float16* __restrict__ h,
                                              float* __restrict__ tacc) {
    int bid = blockIdx.x;
    int head = bid / (NN / 4);             // NN/4 = 2500
    int ng   = bid % (NN / 4);
    int wave = threadIdx.x >> 6, lane = threadIdx.x & 63;
    int n = ng * 4 + wave;                 // always < NN
    int k0 = rowptr[n], deg = rowptr[n + 1] - k0;
    float adv = ad[n * NH + head];
    const _Float16* hh = h + head * C2 + lane;
    float a = 0.f;

    if (deg <= 64) {
        int src = (lane < deg) ? colidx[k0 + lane] : 0;
        float e = (lane < deg) ? leaky(as[(long)src * NH + head] + adv) : -1e30f;
        float m = e;
        for (int mm = 32; mm; mm >>= 1) m = fmaxf(m, __shfl_xor(m, mm));
        float x = (lane < deg) ? __expf(e - m) : 0.f;
        float s = x;
        for (int mm = 32; mm; mm >>= 1) s += __shfl_xor(s, mm);
        float alp = x / (s + 1e-16f);
        int j = 0;
        for (; j + 4 <= deg; j += 4) {
            int s0 = __shfl(src, j),     s1 = __shfl(src, j + 1);
            int s2 = __shfl(src, j + 2), s3 = __shfl(src, j + 3);
            float b0 = __shfl(alp, j),     b1 = __shfl(alp, j + 1);
            float b2 = __shfl(alp, j + 2), b3 = __shfl(alp, j + 3);
            float v0 = (float)hh[(long)s0 * HC2];
            float v1 = (float)hh[(long)s1 * HC2];
            float v2 = (float)hh[(long)s2 * HC2];
            float v3 = (float)hh[(long)s3 * HC2];
            a += b0 * v0 + b1 * v1 + b2 * v2 + b3 * v3;
        }
        for (; j < deg; j++) {
            int sj = __shfl(src, j);
            float bj = __shfl(alp, j);
            a += bj * (float)hh[(long)sj * HC2];
        }
    } else {
        float m = -1e30f;
        for (int j2 = lane; j2 < deg; j2 += 64)
            m = fmaxf(m, leaky(as[(long)colidx[k0 + j2] * NH + head] + adv));
        for (int mm = 32; mm; mm >>= 1) m = fmaxf(m, __shfl_xor(m, mm));
        float s = 0.f;
        for (int j2 = lane; j2 < deg; j2 += 64)
            s += __expf(leaky(as[(long)colidx[k0 + j2] * NH + head] + adv) - m);
        for (int mm = 32; mm; mm >>= 1) s += __shfl_xor(s, mm);
        float inv = 1.f / (s + 1e-16f);
        for (int c0 = 0; c0 < deg; c0 += 64) {
            int cn = min(64, deg - c0);
            int src = (lane < cn) ? colidx[k0 + c0 + lane] : 0;
            float alp = (lane < cn)
                ? __expf(leaky(as[(long)src * NH + head] + adv) - m) * inv : 0.f;
            int j = 0;
            for (; j + 4 <= cn; j += 4) {
                int s0 = __shfl(src, j),     s1 = __shfl(src, j + 1);
                int s2 = __shfl(src, j + 2), s3 = __shfl(src, j + 3);
                float b0 = __shfl(alp, j),     b1 = __shfl(alp, j + 1);
                float b2 = __shfl(alp, j + 2), b3 = __shfl(alp, j + 3);
                a += b0 * (float)hh[(long)s0 * HC2] + b1 * (float)hh[(long)s1 * HC2]
                   + b2 * (float)hh[(long)s2 * HC2] + b3 * (float)hh[(long)s3 * HC2];
            }
            for (; j < cn; j++) {
                int sj = __shfl(src, j);
                float bj = __shfl(alp, j);
                a += bj * (float)hh[(long)sj * HC2];
            }
        }
    }
    atomicAdd(&tacc[n * C2 + lane], a);
}

// ---------------- final: head-mean scale + bias + relu ----------------
__global__ void k_fin(const float* __restrict__ tacc, const float* __restrict__ bias,
                      float* __restrict__ out) {
    int i = blockIdx.x * 256 + threadIdx.x;
    if (i < NN * C2) {
        float s = tacc[i] * 0.1f + bias[i & (C2 - 1)];
        out[i] = s > 0.f ? s : 0.f;
    }
}

// ---------------- host ----------------
extern "C" void kernel_launch(void* const* d_in, const int* in_sizes, int n_in,
                              void* d_out, int out_size, void* d_ws, size_t ws_size,
                              hipStream_t stream) {
    const float* x      = (const float*)d_in[0];
    const int*   ei     = (const int*)d_in[1];
    const float* W1     = (const float*)d_in[2];
    const float* asrc1  = (const float*)d_in[3];
    const float* adst1  = (const float*)d_in[4];
    const float* b1     = (const float*)d_in[5];
    const float* W2     = (const float*)d_in[6];
    const float* asrc2  = (const float*)d_in[7];
    const float* adst2  = (const float*)d_in[8];
    const float* b2     = (const float*)d_in[9];
    float* out = (float*)d_out;
    const int E  = in_sizes[1] / 2;
    const int EN = E + NN;

    char* base = (char*)d_ws;
    size_t o = 0;
    auto alloc = [&](size_t bytes) { size_t r = o; o += (bytes + 255) & ~(size_t)255; return r; };
    _Float16* A1    = (_Float16*)(base + alloc((size_t)MP * K1P * 2));
    _Float16* W1t   = (_Float16*)(base + alloc((size_t)HC1 * K1P * 2));
    _Float16* A2    = (_Float16*)(base + alloc((size_t)MP * HC1 * 2));
    _Float16* W2t   = (_Float16*)(base + alloc((size_t)HC2 * HC1 * 2));
    _Float16* h1pre = (_Float16*)(base + alloc((size_t)MP * HC1 * 2));
    _Float16* h2pre = (_Float16*)(base + alloc((size_t)MP * HC2 * 2));
    float* as1      = (float*)(base + alloc((size_t)NN * NH * 4));
    float* ad1      = (float*)(base + alloc((size_t)NN * NH * 4));
    float* as2      = (float*)(base + alloc((size_t)NN * NH * 4));
    float* ad2      = (float*)(base + alloc((size_t)NN * NH * 4));
    float* tacc     = (float*)(base + alloc((size_t)NN * C2 * 4));
    int* counts     = (int*)(base + alloc((size_t)(NN + 1) * 4));
    int* rowptr     = (int*)(base + alloc((size_t)(NN + 1) * 4));
    int* cursor     = (int*)(base + alloc((size_t)(NN + 1) * 4));
    int* colidx     = (int*)(base + alloc((size_t)EN * 4));
    (void)ws_size; (void)n_in; (void)out_size;

    const int NCNT = (E + 255) / 256;
    const int FILLB = (EN + 511) / 512;                // 512-thr fill blocks
    const int G1 = 8 * (MP / 256 / 8) * (HC1 / 256);   // 200 gemm1 blocks (256x256)
    const int G2 = 8 * (MP / 128 / 8) * (HC2 / 128);   // 400 gemm2 blocks (MFRAG=4)

    // ---- zero counts + tacc; fused prep (cast + transposes + edge count) ----
    hipMemsetAsync(counts, 0, (size_t)(NN + 1) * 4, stream);
    hipMemsetAsync(tacc, 0, (size_t)NN * C2 * 4, stream);
    k_prep<<<NCAST + NW1 + NW2 + NCNT, 256, 0, stream>>>(x, A1, W1, W1t, W2, W2t, ei, counts, E);
    // ---- CSR scan ----
    k_scan<<<1, 1024, 0, stream>>>(counts, rowptr, cursor, NN);
    // ---- layer 1 GEMM (r2 config) + CSR-fill side-jobs ----
    k_gemm1<<<G1 + FILLB, 512, 0, stream>>>(A1, W1t, h1pre, asrc1, adst1, as1, ad1,
                                            G1, ei, cursor, colidx, E);
    // ---- layer 1 agg: head-sliced, head-major grid ----
    k_agg1<<<NH * (MP / 4), 256, 0, stream>>>(rowptr, colidx, as1, ad1, h1pre, b1, A2);
    // ---- layer 2 GEMM ----
    k_gemm<4><<<G2, 256, 0, stream>>>(A2, W2t, h2pre, HC1, HC2, HC2 / 128,
                                      asrc2, adst2, as2, ad2, C2);
    // ---- layer 2 agg: head-sliced partials + finish ----
    k_agg2<<<NH * (NN / 4), 256, 0, stream>>>(rowptr, colidx, as2, ad2, h2pre, tacc);
    k_fin<<<(NN * C2 + 255) / 256, 256, 0, stream>>>(tacc, b2, out);
}